// Round 12
// baseline (983.561 us; speedup 1.0000x reference)
//
#include <hip/hip_runtime.h>
#include <stdint.h>

// Softmax-Viterbi forward, 1024x1024, S=4.
// R20: replace the (involuntary) SCRATCH bounce with an explicit LDS bounce.
// Evidence: R19 VGPR_Count=96 while pA+pB need 128 -> prefetch buffers were
// ALWAYS in scratch; each body pays spill stores + per-step scratch reloads
// (L2/HBM private memory) on the critical path. Correctness survived because
// extra in-window vmem ops make vmcnt(N) over-wait (safe direction). Three
// register-residency attempts failed/crashed (R17/R18); stop fighting the RA.
// New chain structure (single-hc bodies):
//   WAITV(1)  -> retire data(h+1) (issued 1 body ago; ~2400cy lead > ~1000cy
//                system-load latency); only the pace store stays outstanding.
//   ds_write  -> data(h+1) into ldsP[(h+1)&1] (lgkmcnt domain, NOT vmcnt).
//   CHECK/ISSUE flag(h+2)/(h+3); ISSUE_DATA(h+2) into the freed named temps.
//   COMPUTE hc h from ldsP[h&1] (ds_read_b128, compiler-scheduled).
//   CHCTAIL: F_CDONE post + pace store (last vmem op of the body).
// vmcnt stream: 18 ops/body (flag, data x16, pace), flag issued BEFORE data
// so WAITV(1) retires flag+data exactly. Live set ~64 temp + ~40 state regs.
// Producers / out-comms / in-comms / pace flow / ws layout: frozen from R19.

typedef float f32x4 __attribute__((ext_vector_type(4)));
typedef int   i32x4 __attribute__((ext_vector_type(4)));

#define MM    1024
#define LOG2E 1.4426950408889634f
#define LN2f  0.6931471805599453f
#define NEGI  (-1073741824)
#define NCH   136
#define HCT   (NCH*2)                // 272 half-chunks, 4 steps each
#define DEPTH 32                     // global P-ring depth in half-chunks
#define PPS   15                     // producer blocks per strip

#define F_RIN   0
#define F_CDONE 1
#define F_OPUB  2

__device__ __forceinline__ float ld_cohf(const float* p) {
    return __hip_atomic_load(p, __ATOMIC_RELAXED, __HIP_MEMORY_SCOPE_AGENT);
}
__device__ __forceinline__ int ld_cohi(const int* p) {
    return __hip_atomic_load(p, __ATOMIC_RELAXED, __HIP_MEMORY_SCOPE_AGENT);
}
__device__ __forceinline__ void st_cohf(float* p, float v) {
    __hip_atomic_store(p, v, __ATOMIC_RELAXED, __HIP_MEMORY_SCOPE_AGENT);
}
__device__ __forceinline__ void st_cohi(int* p, int v) {
    __hip_atomic_store(p, v, __ATOMIC_RELAXED, __HIP_MEMORY_SCOPE_AGENT);
}
__device__ __forceinline__ int lds_acq(const int* p) {
    return __hip_atomic_load(p, __ATOMIC_ACQUIRE, __HIP_MEMORY_SCOPE_WORKGROUP);
}
__device__ __forceinline__ void lds_rel(int* p, int v) {
    __hip_atomic_store(p, v, __ATOMIC_RELEASE, __HIP_MEMORY_SCOPE_WORKGROUP);
}

// DPP wave_shr1: lane n <- lane n-1; lane 0 <- oldv (bound_ctrl=false keeps old).
__device__ __forceinline__ int dpp_shr1_i(int oldv, int src) {
    return __builtin_amdgcn_update_dpp(oldv, src, 0x138, 0xF, 0xF, false);
}
__device__ __forceinline__ float dpp_shr1_f(float oldv, float src) {
    return __int_as_float(__builtin_amdgcn_update_dpp(
        __float_as_int(oldv), __float_as_int(src), 0x138, 0xF, 0xF, false));
}

// ---------------- chain-side pipeline macros ----------------
#define WAITV(N) do {                                                         \
    asm volatile("s_waitcnt vmcnt(" #N ")" ::: "memory");                     \
    __builtin_amdgcn_sched_barrier(0);                                        \
} while (0)

#define ISSUE_FLAG(FX, H) do {                                                \
    const int hf_ = ((H) < HCT ? (H) : (HCT-1));                              \
    const int* rp_ = rfS + (size_t)(hf_ & (DEPTH-1)) * 16;                    \
    asm volatile("global_load_dwordx4 %0, %1, off sc0 sc1"                    \
                 : "=v"(FX) : "v"(rp_) : "memory");                           \
} while (0)

#define CHECK_FLAG(FX, H) do {                                                \
    const int hv_ = ((H) < HCT ? (H) : (HCT-1));                              \
    if (!(FX.x >= hv_ && FX.y >= hv_ && FX.z >= hv_ && FX.w >= hv_)) {        \
        const int* rp_ = rfS + (size_t)(hv_ & (DEPTH-1)) * 16;                \
        for (;;) {                                                            \
            asm volatile("global_load_dwordx4 %0, %1, off sc0 sc1\n\t"        \
                         "s_waitcnt vmcnt(0)"                                 \
                         : "=v"(FX) : "v"(rp_) : "memory");                   \
            if (FX.x >= hv_ && FX.y >= hv_ && FX.z >= hv_ && FX.w >= hv_)     \
                break;                                                        \
            __builtin_amdgcn_s_sleep(2);                                      \
        }                                                                     \
    }                                                                         \
    asm volatile("" ::: "memory");                                            \
} while (0)

// Named-register temp buffer: 16 individually named f32x4 (arrays with
// asm-bound elements get demoted to scratch -- R13-R19 lesson).
#define DECLP(PX) f32x4 PX##0, PX##1, PX##2, PX##3, PX##4, PX##5, PX##6,      \
                        PX##7, PX##8, PX##9, PX##10, PX##11, PX##12,          \
                        PX##13, PX##14, PX##15

#define ISSUE_DATA(PX, H) do {                                                \
    const int hcl_ = ((H) < HCT ? (H) : (HCT-1));                             \
    const char* b0_ = ringS + ((size_t)(hcl_ & (DEPTH-1)) << 14)              \
                            + (size_t)lane * 16;                              \
    const char* b1_ = b0_ + 4096;                                             \
    const char* b2_ = b0_ + 8192;                                             \
    const char* b3_ = b0_ + 12288;                                            \
    asm volatile("global_load_dwordx4 %0, %1, off sc0 sc1"              : "=v"(PX##0)  : "v"(b0_) : "memory"); \
    asm volatile("global_load_dwordx4 %0, %1, off offset:1024 sc0 sc1"  : "=v"(PX##1)  : "v"(b0_) : "memory"); \
    asm volatile("global_load_dwordx4 %0, %1, off offset:2048 sc0 sc1"  : "=v"(PX##2)  : "v"(b0_) : "memory"); \
    asm volatile("global_load_dwordx4 %0, %1, off offset:3072 sc0 sc1"  : "=v"(PX##3)  : "v"(b0_) : "memory"); \
    asm volatile("global_load_dwordx4 %0, %1, off sc0 sc1"              : "=v"(PX##4)  : "v"(b1_) : "memory"); \
    asm volatile("global_load_dwordx4 %0, %1, off offset:1024 sc0 sc1"  : "=v"(PX##5)  : "v"(b1_) : "memory"); \
    asm volatile("global_load_dwordx4 %0, %1, off offset:2048 sc0 sc1"  : "=v"(PX##6)  : "v"(b1_) : "memory"); \
    asm volatile("global_load_dwordx4 %0, %1, off offset:3072 sc0 sc1"  : "=v"(PX##7)  : "v"(b1_) : "memory"); \
    asm volatile("global_load_dwordx4 %0, %1, off sc0 sc1"              : "=v"(PX##8)  : "v"(b2_) : "memory"); \
    asm volatile("global_load_dwordx4 %0, %1, off offset:1024 sc0 sc1"  : "=v"(PX##9)  : "v"(b2_) : "memory"); \
    asm volatile("global_load_dwordx4 %0, %1, off offset:2048 sc0 sc1"  : "=v"(PX##10) : "v"(b2_) : "memory"); \
    asm volatile("global_load_dwordx4 %0, %1, off offset:3072 sc0 sc1"  : "=v"(PX##11) : "v"(b2_) : "memory"); \
    asm volatile("global_load_dwordx4 %0, %1, off sc0 sc1"              : "=v"(PX##12) : "v"(b3_) : "memory"); \
    asm volatile("global_load_dwordx4 %0, %1, off offset:1024 sc0 sc1"  : "=v"(PX##13) : "v"(b3_) : "memory"); \
    asm volatile("global_load_dwordx4 %0, %1, off offset:2048 sc0 sc1"  : "=v"(PX##14) : "v"(b3_) : "memory"); \
    asm volatile("global_load_dwordx4 %0, %1, off offset:3072 sc0 sc1"  : "=v"(PX##15) : "v"(b3_) : "memory"); \
} while (0)

// LDS bounce: write the 16 named temps into ldsP[B] (lgkmcnt domain).
#define DSWRITE(B, PX) do {                                                   \
    ldsP[(B)][0][lane]  = PX##0;  ldsP[(B)][1][lane]  = PX##1;                \
    ldsP[(B)][2][lane]  = PX##2;  ldsP[(B)][3][lane]  = PX##3;                \
    ldsP[(B)][4][lane]  = PX##4;  ldsP[(B)][5][lane]  = PX##5;                \
    ldsP[(B)][6][lane]  = PX##6;  ldsP[(B)][7][lane]  = PX##7;                \
    ldsP[(B)][8][lane]  = PX##8;  ldsP[(B)][9][lane]  = PX##9;                \
    ldsP[(B)][10][lane] = PX##10; ldsP[(B)][11][lane] = PX##11;               \
    ldsP[(B)][12][lane] = PX##12; ldsP[(B)][13][lane] = PX##13;               \
    ldsP[(B)][14][lane] = PX##14; ldsP[(B)][15][lane] = PX##15;               \
} while (0)

#define CHUNKSPIN(H) do {                                                     \
    if (((H) & 1) == 0) {                                                     \
        const int cc_ = (H) >> 1;                                             \
        if (isCons) while (lds_acq(&flags[F_RIN]) < cc_) {}                   \
        if (isProd) while (lds_acq(&flags[F_OPUB]) < cc_ - 3) {}              \
    }                                                                         \
} while (0)

// One cell-step. LP = LDS buffer row pointer (f32x4 [16][64]).
// BB/BM = preloaded boundary record (R19 hoist).
#define VSTEP(H, U, LP, DO_CLAMP, DO_NORM, BB, BM) do {                       \
    const int sb_ = (((H) >> 1) & 3) * 8 + ((H) & 1) * 4 + (U);               \
    f32x4 P0 = LP[(U)*4+0][lane], P1 = LP[(U)*4+1][lane];                     \
    f32x4 P2 = LP[(U)*4+2][lane], P3 = LP[(U)*4+3][lane];                     \
    int off = max(max(mD, mU), mL);                                           \
    float sd = ldexpf(1.0f, mD - off);                                        \
    float su = ldexpf(1.0f, mU - off);                                        \
    float sl = ldexpf(1.0f, mL - off);                                        \
    float dm  = fmaf(qd3,P0.w, fmaf(qd2,P0.z, fmaf(qd1,P0.y, qd0*P0.x)));     \
    float dx  = fmaf(qu3,P1.w, fmaf(qu2,P1.z, fmaf(qu1,P1.y, qu0*P1.x)));     \
    float dy  = fmaf(ql3,P2.w, fmaf(ql2,P2.z, fmaf(ql1,P2.y, ql0*P2.x)));     \
    float ds2 = fmaf(qd3,P3.w, fmaf(qd2,P3.z, fmaf(qd1,P3.y, qd0*P3.x)));     \
    float qn0 = dm*sd, qn1 = dx*su, qn2 = dy*sl, qn3 = ds2*sd;                \
    int mn = off;                                                             \
    if (DO_NORM) {                                                            \
        float gmax = fmaxf(fmaxf(qn0,qn1), fmaxf(qn2,qn3));                   \
        int e = (int)(__float_as_uint(gmax) >> 23) - 126;                     \
        qn0 = ldexpf(qn0, 1-e); qn1 = ldexpf(qn1, 1-e);                       \
        qn2 = ldexpf(qn2, 1-e); qn3 = ldexpf(qn3, 1-e);                       \
        mn = off + e - 1;                                                     \
    }                                                                         \
    if (DO_CLAMP) {                                                           \
        const int jq_ = (H)*4 + (U) - r + 1;                                  \
        const bool valid_ = (jq_ >= 1) && (jq_ <= MM);                        \
        if (!valid_) { qn0=qn1=qn2=qn3=0.f; mn=NEGI; }                        \
        if (!isProd && lane == 63 && jq_ == MM)                               \
            out[0] = LN2f * ((float)mn + log2f((qn0+qn1)+(qn2+qn3)));         \
    }                                                                         \
    if (isProd && lane == 63) {                                               \
        *(float4*)&recOut[sb_][0] = make_float4(qn0,qn1,qn2,qn3);             \
        recOut[sb_][4] = __int_as_float(mn);                                  \
    }                                                                         \
    mD = mU; qd0=qu0; qd1=qu1; qd2=qu2; qd3=qu3;                              \
    mU  = dpp_shr1_i(BM, mn);                                                 \
    qu0 = dpp_shr1_f(BB.x, qn0);                                              \
    qu1 = dpp_shr1_f(BB.y, qn1);                                              \
    qu2 = dpp_shr1_f(BB.z, qn2);                                              \
    qu3 = dpp_shr1_f(BB.w, qn3);                                              \
    mL = mn; ql0=qn0; ql1=qn1; ql2=qn2; ql3=qn3;                              \
} while (0)

// Hoisted boundary-record loads (R19): all 4 records of the hc, batched.
#define LOADREC(H)                                                            \
    const int sbh_ = (((H) >> 1) & 3) * 8 + ((H) & 1) * 4;                    \
    float4 bb0_ = make_float4(0.f,0.f,0.f,0.f), bb1_ = bb0_,                  \
           bb2_ = bb0_, bb3_ = bb0_;                                          \
    int bm0_ = NEGI, bm1_ = NEGI, bm2_ = NEGI, bm3_ = NEGI;                   \
    if (isCons) {                                                             \
        bb0_ = *(const float4*)&recIn[sbh_+0][0];                             \
        bb1_ = *(const float4*)&recIn[sbh_+1][0];                             \
        bb2_ = *(const float4*)&recIn[sbh_+2][0];                             \
        bb3_ = *(const float4*)&recIn[sbh_+3][0];                             \
        bm0_ = __float_as_int(recIn[sbh_+0][4]);                              \
        bm1_ = __float_as_int(recIn[sbh_+1][4]);                              \
        bm2_ = __float_as_int(recIn[sbh_+2][4]);                              \
        bm3_ = __float_as_int(recIn[sbh_+3][4]);                              \
    }

// chain tail: LDS progress post + pace store (last vmem op of the body).
#define CHCTAIL(H) do {                                                       \
    asm volatile("" ::: "memory");                                            \
    if (lane == 0) {                                                          \
        *(volatile int*)&flags[F_CDONE] = (H);  /* LDS in-order per wave */   \
        st_cohi(cp, (H));                       /* pace producers */          \
    }                                                                         \
} while (0)

#define COMPUTEHC_C(H, B) do {                                                \
    const f32x4 (*Lp_)[64] = ldsP[(B)];                                       \
    LOADREC(H);                                                               \
    VSTEP(H,0,Lp_,1,1,bb0_,bm0_); VSTEP(H,1,Lp_,1,1,bb1_,bm1_);               \
    VSTEP(H,2,Lp_,1,1,bb2_,bm2_); VSTEP(H,3,Lp_,1,1,bb3_,bm3_);               \
    CHCTAIL(H);                                                               \
} while (0)

// FAST: all lanes valid; normalize every other step (last step normalized).
#define COMPUTEHC_F(H, B) do {                                                \
    const f32x4 (*Lp_)[64] = ldsP[(B)];                                       \
    LOADREC(H);                                                               \
    VSTEP(H,0,Lp_,0,0,bb0_,bm0_); VSTEP(H,1,Lp_,0,1,bb1_,bm1_);               \
    VSTEP(H,2,Lp_,0,0,bb2_,bm2_); VSTEP(H,3,Lp_,0,1,bb3_,bm3_);               \
    CHCTAIL(H);                                                               \
} while (0)

// steady-state single-hc body. vmem order per body: flag(h+3), data(h+2)x16,
// pace(h). At body h+1's WAITV(1): outstanding = {flag, data x16, pace};
// retiring to <=1 leaves only pace -> flag AND data retired exactly.
#define CHAINBODY(H, CHC) do {                                                \
    CHUNKSPIN(H);                                                             \
    WAITV(1);                                                                 \
    DSWRITE(((H)+1)&1, t_);                                                   \
    __builtin_amdgcn_sched_barrier(0);                                        \
    CHECK_FLAG(fA, (H)+2); ISSUE_FLAG(fA, (H)+3);                             \
    ISSUE_DATA(t_, (H)+2);                                                    \
    CHC((H), ((H)&1));                                                        \
    CHCTAIL(H);                                                               \
} while (0)

__global__ __launch_bounds__(256, 1) void viterbi_r20(
    const float* __restrict__ theta, const float* __restrict__ A,
    float* __restrict__ out, float* __restrict__ bnd, int* __restrict__ prog,
    int* __restrict__ cpG, int* __restrict__ rfG, float* __restrict__ ringG)
{
    __shared__ f32x4  ldsP[2][16][64];          // 32 KB LDS bounce buffer
    __shared__ float  recIn[32][8];
    __shared__ float  recOut[32][8];
    __shared__ int    flags[16];
    extern __shared__ char dynpad[];            // 64 KB pad -> ~99 KB total
    (void)dynpad;                               //   -> 1 block/CU

    const int tid  = threadIdx.x;
    const int wv   = tid >> 6;
    const int lane = tid & 63;
    const int bid  = blockIdx.x;

    if (tid < 16) flags[tid] = -1;
    __syncthreads();

    if (bid >= 16) {
        // ===================== producer blocks (4 waves) ====================
        const int k     = bid & 7;           // XCD (heuristic)
        const int idx   = (bid - 16) >> 3;   // 0..29 within XCD
        const int s     = 2*k + (idx >= PPS);
        const int pslot = idx % PPS;
        const int u2    = wv;                // tau within hc
        const int row   = s*64 + lane;
        const float4* A4 = (const float4*)A;
        const float4* T4 = (const float4*)theta;
        const int* cp = cpG + s*16;
        for (int h = pslot; h < HCT; h += PPS) {
            while (ld_cohi(cp) < h - DEPTH) __builtin_amdgcn_s_sleep(1);
            const int tau = 4*h + u2;
            int c = tau - lane; c = c < 0 ? 0 : (c > MM-1 ? MM-1 : c);
            const float4* Ar = A4 + ((size_t)row*MM + (size_t)c)*4;
            float4 a0 = Ar[0], a1 = Ar[1], a2 = Ar[2], a3 = Ar[3];
            float4 th = T4[(size_t)row*MM + (size_t)c];
            float4 p0, p1, p2, p3;       // theta-folded exp-domain potentials
            p0.x=exp2f((a0.x+th.x)*LOG2E); p0.y=exp2f((a0.y+th.x)*LOG2E);
            p0.z=exp2f((a0.z+th.x)*LOG2E); p0.w=exp2f((a0.w+th.x)*LOG2E);
            p1.x=exp2f((a1.x+th.y)*LOG2E); p1.y=exp2f((a1.y+th.y)*LOG2E);
            p1.z=exp2f((a1.z+th.y)*LOG2E); p1.w=exp2f((a1.w+th.y)*LOG2E);
            p2.x=exp2f((a2.x+th.z)*LOG2E); p2.y=exp2f((a2.y+th.z)*LOG2E);
            p2.z=exp2f((a2.z+th.z)*LOG2E); p2.w=exp2f((a2.w+th.z)*LOG2E);
            p3.x=exp2f((a3.x+th.w)*LOG2E); p3.y=exp2f((a3.y+th.w)*LOG2E);
            p3.z=exp2f((a3.z+th.w)*LOG2E); p3.w=exp2f((a3.w+th.w)*LOG2E);
            float* dst = ringG + ((size_t)(s*DEPTH + (h & (DEPTH-1))) << 12)
                               + (size_t)((u2*4)*64 + lane)*4;
            st_cohf(dst+0,   p0.x); st_cohf(dst+1,   p0.y);
            st_cohf(dst+2,   p0.z); st_cohf(dst+3,   p0.w);
            st_cohf(dst+256, p1.x); st_cohf(dst+257, p1.y);
            st_cohf(dst+258, p1.z); st_cohf(dst+259, p1.w);
            st_cohf(dst+512, p2.x); st_cohf(dst+513, p2.y);
            st_cohf(dst+514, p2.z); st_cohf(dst+515, p2.w);
            st_cohf(dst+768, p3.x); st_cohf(dst+769, p3.y);
            st_cohf(dst+770, p3.z); st_cohf(dst+771, p3.w);
            asm volatile("s_waitcnt vmcnt(0)" ::: "memory");
            if (lane == 0)
                st_cohi(rfG + (size_t)(s*DEPTH + (h & (DEPTH-1)))*16 + u2, h);
        }
        return;
    }

    // ===================== pipeline blocks =====================
    const int strip = ((bid & 7) << 1) | (bid >> 3);
    const bool isCons = (strip > 0);
    const bool isProd = (strip < 15);

    float* Prec = bnd + (size_t)strip * MM * 8;
    const float* Crec = bnd + (size_t)(strip - 1) * MM * 8;
    int* myflag = prog + strip * 32;
    const int* upflag = prog + (strip - 1) * 32;

    if (wv == 0) {
        // ===== chain wave: single-temp + LDS-bounce counted pipeline ========
        __builtin_amdgcn_s_setprio(1);
        const int r = lane;
        int   mL = NEGI, mU = NEGI, mD = NEGI;
        float ql0=0,ql1=0,ql2=0,ql3=0;
        float qu0=0,qu1=0,qu2=0,qu3=0;
        float qd0=0,qd1=0,qd2=0,qd3=0;
        if (strip == 0 && lane == 0) { mD = 0; qd0=qd1=qd2=qd3=1.f; }
        if (isCons) {
            while (ld_cohi(upflag) < 1) __builtin_amdgcn_s_sleep(1);
            asm volatile("" ::: "memory");
            qu0 = ld_cohf(Crec+0); qu1 = ld_cohf(Crec+1);
            qu2 = ld_cohf(Crec+2); qu3 = ld_cohf(Crec+3);
            mU  = ld_cohi((const int*)Crec + 4);
        }
        int* cp = cpG + strip*16;
        const int* rfS = rfG + (size_t)strip * DEPTH * 16;
        const char* ringS = (const char*)ringG + ((size_t)strip * DEPTH << 14);
        if (lane == 0) st_cohi(cp, -1);      // unblock producers h < DEPTH

        DECLP(t_);
        i32x4 fA = {-2,-2,-2,-2};
        // prologue: hc0 -> LDS buf0; data(1) + flag(2) in flight.
        CHECK_FLAG(fA, 0); ISSUE_DATA(t_, 0);
        WAITV(0);
        DSWRITE(0, t_);
        __builtin_amdgcn_sched_barrier(0);
        CHECK_FLAG(fA, 1);                   // one-time poll (fA stale)
        ISSUE_FLAG(fA, 2); ISSUE_DATA(t_, 1);
        // body 0 (one-time full drain: flag(2) issued before data(1)? no --
        // flag(2) issued first above, data(1) after; WAITV(0) drains both)
        CHUNKSPIN(0);
        WAITV(0);
        DSWRITE(1, t_);
        __builtin_amdgcn_sched_barrier(0);
        CHECK_FLAG(fA, 2); ISSUE_FLAG(fA, 3);
        ISSUE_DATA(t_, 2);
        COMPUTEHC_C(0, 0);
        CHCTAIL(0);
        // clamped prologue: hc 1..15
        for (int h = 1; h < 16; ++h)   CHAINBODY(h, COMPUTEHC_C);
        // fast body: hc 16..255 (taus 64..1023, all lanes valid)
        for (int h = 16; h < 256; ++h) CHAINBODY(h, COMPUTEHC_F);
        // clamped epilogue: hc 256..271
        for (int h = 256; h < HCT; ++h) CHAINBODY(h, COMPUTEHC_C);
    } else if (wv == 1) {
        // ===================== out-comms wave =====================
        if (!isProd) return;
        const int rec0 = lane / 5, wd0 = lane % 5;
        const int rec1 = (lane+64) / 5, wd1 = (lane+64) % 5;
        const bool on1 = (lane + 64) < 80;
        for (int cc = 0; cc < NCH; cc += 2) {
            while (lds_acq(&flags[F_CDONE]) < 2*cc + 3) __builtin_amdgcn_s_sleep(1);
            {
                int col = 8*(cc + (rec0 >> 3)) + (rec0 & 7) - 62;
                float v = recOut[(cc & 3)*8 + rec0][wd0];
                if (col >= 1 && col <= MM) st_cohf(Prec + (size_t)(col-1)*8 + wd0, v);
            }
            if (on1) {
                int col = 8*(cc + (rec1 >> 3)) + (rec1 & 7) - 62;
                float v = recOut[(cc & 3)*8 + rec1][wd1];
                if (col >= 1 && col <= MM) st_cohf(Prec + (size_t)(col-1)*8 + wd1, v);
            }
            asm volatile("s_waitcnt vmcnt(0)" ::: "memory");
            int done = 8*(cc + 1) - 55; if (done > MM) done = MM;
            if (done >= 1 && lane == 0) st_cohi(myflag, done);
            if (lane == 0) lds_rel(&flags[F_OPUB], cc + 1);
        }
    } else if (wv == 2) {
        // ===================== in-comms wave =====================
        if (!isCons) return;
        const int rec0 = lane / 5, wd0 = lane % 5;
        const int rec1 = (lane+64) / 5, wd1 = (lane+64) % 5;
        const bool on1 = (lane + 64) < 80;
        for (int cc = 0; cc < NCH; cc += 2) {
            while (lds_acq(&flags[F_CDONE]) < 2*cc - 3) __builtin_amdgcn_s_sleep(1);
            int need = 8*cc + 17; if (need > MM) need = MM;
            while (ld_cohi(upflag) < need) __builtin_amdgcn_s_sleep(1);
            asm volatile("" ::: "memory");
            {
                int col = 8*cc + 2 + rec0; if (col > MM) col = MM;
                float v = ld_cohf(Crec + (size_t)(col-1)*8 + wd0);
                recIn[(cc & 3)*8 + rec0][wd0] = v;
            }
            if (on1) {
                int col = 8*cc + 2 + rec1; if (col > MM) col = MM;
                float v = ld_cohf(Crec + (size_t)(col-1)*8 + wd1);
                recIn[(cc & 3)*8 + rec1][wd1] = v;
            }
            if (lane == 0) lds_rel(&flags[F_RIN], cc + 1);
        }
    }
    // wv == 3: idle
}

extern "C" void kernel_launch(void* const* d_in, const int* in_sizes, int n_in,
                              void* d_out, int out_size, void* d_ws, size_t ws_size,
                              hipStream_t stream) {
    const float* theta = (const float*)d_in[0];   // [1024,1024,4] f32
    const float* A     = (const float*)d_in[1];   // [1024,1024,4,4] f32
    float* out = (float*)d_out;                   // [1] f32
    // ws layout (0xAA poison -> all flags/counters negative -> safe spins):
    //   [0, 512K)        boundary records [16][1024][8] f32
    //   [512K, 512K+4K)  record progress flags prog[16*32]
    //   [+4K, +8K)       chain progress cpG[16*16]
    //   [+8K, +40K)      ring flags rfG[16*32*16]
    //   [64K-aligned 8M) P ring ringG: 16 strips * 32 slots * 16 KB
    char* base = (char*)d_ws;
    float* bnd  = (float*)base;
    int*   prog = (int*)(base + (size_t)512*1024);
    int*   cpG  = (int*)(base + (size_t)512*1024 + 4*1024);
    int*   rfG  = (int*)(base + (size_t)512*1024 + 8*1024);
    float* ring = (float*)(base + (size_t)512*1024 + 64*1024);
    // 64 KB dynamic pad + ~35 KB static = ~99 KB -> 1 block/CU.
    viterbi_r20<<<256, 256, 64*1024, stream>>>(theta, A, out, bnd, prog,
                                               cpG, rfG, ring);
}

// Round 13
// 564.881 us; speedup vs baseline: 1.7412x; 1.7412x over previous
//
#include <hip/hip_runtime.h>
#include <stdint.h>

// Softmax-Viterbi forward, 1024x1024, S=4.
// R21 = R19 EXACTLY (best verified 537us: 2-deep counted prefetch, hoisted
// recIn reads, 3-phase norm/clamp) with ONE isolated change: the pace store
// (st_cohi, agent-scope) removed from the chain's counted vmcnt stream.
// Rationale: vmcnt retires in issue order; R19's per-body stream was
// [flag, PACE STORE, data x16] so WAITV(19) retired a coherent store-ACK
// every body before the data became usable. R15 tested this removal but
// bundled it with 3-deep buffers that spilled (VGPR 124<192, scratch ops
// corrupt vmcnt counts) -> its regression indicts the depth, not the store.
// Here: wv3 mirrors F_CDONE (LDS) -> cpG (global); chain stream is pure
// loads, 17 ops/body; steady waits W1=33 / W2=18; prologue WAITV(1)/(17).
// R20 lesson kept: prefetch lead stays 2 hc (~1250cy > ~1000cy sys-load lat).
// Producers (h>=DEPTH pace guard) / out-comms / in-comms / ws layout frozen.

typedef float f32x4 __attribute__((ext_vector_type(4)));
typedef int   i32x4 __attribute__((ext_vector_type(4)));

#define MM    1024
#define LOG2E 1.4426950408889634f
#define LN2f  0.6931471805599453f
#define NEGI  (-1073741824)
#define NCH   136
#define HCT   (NCH*2)                // 272 half-chunks, 4 steps each
#define DEPTH 32                     // global P-ring depth in half-chunks
#define PPS   15                     // producer blocks per strip

#define F_RIN   0
#define F_CDONE 1
#define F_OPUB  2

__device__ __forceinline__ float ld_cohf(const float* p) {
    return __hip_atomic_load(p, __ATOMIC_RELAXED, __HIP_MEMORY_SCOPE_AGENT);
}
__device__ __forceinline__ int ld_cohi(const int* p) {
    return __hip_atomic_load(p, __ATOMIC_RELAXED, __HIP_MEMORY_SCOPE_AGENT);
}
__device__ __forceinline__ void st_cohf(float* p, float v) {
    __hip_atomic_store(p, v, __ATOMIC_RELAXED, __HIP_MEMORY_SCOPE_AGENT);
}
__device__ __forceinline__ void st_cohi(int* p, int v) {
    __hip_atomic_store(p, v, __ATOMIC_RELAXED, __HIP_MEMORY_SCOPE_AGENT);
}
__device__ __forceinline__ int lds_acq(const int* p) {
    return __hip_atomic_load(p, __ATOMIC_ACQUIRE, __HIP_MEMORY_SCOPE_WORKGROUP);
}
__device__ __forceinline__ void lds_rel(int* p, int v) {
    __hip_atomic_store(p, v, __ATOMIC_RELEASE, __HIP_MEMORY_SCOPE_WORKGROUP);
}

// DPP wave_shr1: lane n <- lane n-1; lane 0 <- oldv (bound_ctrl=false keeps old).
__device__ __forceinline__ int dpp_shr1_i(int oldv, int src) {
    return __builtin_amdgcn_update_dpp(oldv, src, 0x138, 0xF, 0xF, false);
}
__device__ __forceinline__ float dpp_shr1_f(float oldv, float src) {
    return __int_as_float(__builtin_amdgcn_update_dpp(
        __float_as_int(oldv), __float_as_int(src), 0x138, 0xF, 0xF, false));
}

// ---------------- chain-side pipeline macros ----------------
#define WAITV(N) do {                                                         \
    asm volatile("s_waitcnt vmcnt(" #N ")" ::: "memory");                     \
    __builtin_amdgcn_sched_barrier(0);                                        \
} while (0)

#define ISSUE_FLAG(FX, H) do {                                                \
    const int hf_ = ((H) < HCT ? (H) : (HCT-1));                              \
    const int* rp_ = rfS + (size_t)(hf_ & (DEPTH-1)) * 16;                    \
    asm volatile("global_load_dwordx4 %0, %1, off sc0 sc1"                    \
                 : "=v"(FX) : "v"(rp_) : "memory");                           \
} while (0)

#define CHECK_FLAG(FX, H) do {                                                \
    const int hv_ = ((H) < HCT ? (H) : (HCT-1));                              \
    if (!(FX.x >= hv_ && FX.y >= hv_ && FX.z >= hv_ && FX.w >= hv_)) {        \
        const int* rp_ = rfS + (size_t)(hv_ & (DEPTH-1)) * 16;                \
        for (;;) {                                                            \
            asm volatile("global_load_dwordx4 %0, %1, off sc0 sc1\n\t"        \
                         "s_waitcnt vmcnt(0)"                                 \
                         : "=v"(FX) : "v"(rp_) : "memory");                   \
            if (FX.x >= hv_ && FX.y >= hv_ && FX.z >= hv_ && FX.w >= hv_)     \
                break;                                                        \
            __builtin_amdgcn_s_sleep(2);                                      \
        }                                                                     \
    }                                                                         \
    asm volatile("" ::: "memory");                                            \
} while (0)

#define ISSUE_DATA(PX, H) do {                                                \
    const int hcl_ = ((H) < HCT ? (H) : (HCT-1));                             \
    const char* b0_ = ringS + ((size_t)(hcl_ & (DEPTH-1)) << 14)              \
                            + (size_t)lane * 16;                              \
    const char* b1_ = b0_ + 4096;                                             \
    const char* b2_ = b0_ + 8192;                                             \
    const char* b3_ = b0_ + 12288;                                            \
    asm volatile("global_load_dwordx4 %0, %1, off sc0 sc1"              : "=v"(PX[0])  : "v"(b0_) : "memory"); \
    asm volatile("global_load_dwordx4 %0, %1, off offset:1024 sc0 sc1"  : "=v"(PX[1])  : "v"(b0_) : "memory"); \
    asm volatile("global_load_dwordx4 %0, %1, off offset:2048 sc0 sc1"  : "=v"(PX[2])  : "v"(b0_) : "memory"); \
    asm volatile("global_load_dwordx4 %0, %1, off offset:3072 sc0 sc1"  : "=v"(PX[3])  : "v"(b0_) : "memory"); \
    asm volatile("global_load_dwordx4 %0, %1, off sc0 sc1"              : "=v"(PX[4])  : "v"(b1_) : "memory"); \
    asm volatile("global_load_dwordx4 %0, %1, off offset:1024 sc0 sc1"  : "=v"(PX[5])  : "v"(b1_) : "memory"); \
    asm volatile("global_load_dwordx4 %0, %1, off offset:2048 sc0 sc1"  : "=v"(PX[6])  : "v"(b1_) : "memory"); \
    asm volatile("global_load_dwordx4 %0, %1, off offset:3072 sc0 sc1"  : "=v"(PX[7])  : "v"(b1_) : "memory"); \
    asm volatile("global_load_dwordx4 %0, %1, off sc0 sc1"              : "=v"(PX[8])  : "v"(b2_) : "memory"); \
    asm volatile("global_load_dwordx4 %0, %1, off offset:1024 sc0 sc1"  : "=v"(PX[9])  : "v"(b2_) : "memory"); \
    asm volatile("global_load_dwordx4 %0, %1, off offset:2048 sc0 sc1"  : "=v"(PX[10]) : "v"(b2_) : "memory"); \
    asm volatile("global_load_dwordx4 %0, %1, off offset:3072 sc0 sc1"  : "=v"(PX[11]) : "v"(b2_) : "memory"); \
    asm volatile("global_load_dwordx4 %0, %1, off sc0 sc1"              : "=v"(PX[12]) : "v"(b3_) : "memory"); \
    asm volatile("global_load_dwordx4 %0, %1, off offset:1024 sc0 sc1"  : "=v"(PX[13]) : "v"(b3_) : "memory"); \
    asm volatile("global_load_dwordx4 %0, %1, off offset:2048 sc0 sc1"  : "=v"(PX[14]) : "v"(b3_) : "memory"); \
    asm volatile("global_load_dwordx4 %0, %1, off offset:3072 sc0 sc1"  : "=v"(PX[15]) : "v"(b3_) : "memory"); \
} while (0)

#define CHUNKSPIN(H) do {                                                     \
    if (((H) & 1) == 0) {                                                     \
        const int cc_ = (H) >> 1;                                             \
        if (isCons) while (lds_acq(&flags[F_RIN]) < cc_) {}                   \
        if (isProd) while (lds_acq(&flags[F_OPUB]) < cc_ - 3) {}              \
    }                                                                         \
} while (0)

// One cell-step. BB/BM = PRELOADED boundary record (R19 hoist).
#define VSTEP(H, U, PX, DO_CLAMP, DO_NORM, BB, BM) do {                       \
    const int sb_ = (((H) >> 1) & 3) * 8 + ((H) & 1) * 4 + (U);               \
    f32x4 P0 = PX[(U)*4+0], P1 = PX[(U)*4+1];                                 \
    f32x4 P2 = PX[(U)*4+2], P3 = PX[(U)*4+3];                                 \
    int off = max(max(mD, mU), mL);                                           \
    float sd = ldexpf(1.0f, mD - off);                                        \
    float su = ldexpf(1.0f, mU - off);                                        \
    float sl = ldexpf(1.0f, mL - off);                                        \
    float dm  = fmaf(qd3,P0.w, fmaf(qd2,P0.z, fmaf(qd1,P0.y, qd0*P0.x)));     \
    float dx  = fmaf(qu3,P1.w, fmaf(qu2,P1.z, fmaf(qu1,P1.y, qu0*P1.x)));     \
    float dy  = fmaf(ql3,P2.w, fmaf(ql2,P2.z, fmaf(ql1,P2.y, ql0*P2.x)));     \
    float ds2 = fmaf(qd3,P3.w, fmaf(qd2,P3.z, fmaf(qd1,P3.y, qd0*P3.x)));     \
    float qn0 = dm*sd, qn1 = dx*su, qn2 = dy*sl, qn3 = ds2*sd;                \
    int mn = off;                                                             \
    if (DO_NORM) {                                                            \
        float gmax = fmaxf(fmaxf(qn0,qn1), fmaxf(qn2,qn3));                   \
        int e = (int)(__float_as_uint(gmax) >> 23) - 126;                     \
        qn0 = ldexpf(qn0, 1-e); qn1 = ldexpf(qn1, 1-e);                       \
        qn2 = ldexpf(qn2, 1-e); qn3 = ldexpf(qn3, 1-e);                       \
        mn = off + e - 1;                                                     \
    }                                                                         \
    if (DO_CLAMP) {                                                           \
        const int jq_ = (H)*4 + (U) - r + 1;                                  \
        const bool valid_ = (jq_ >= 1) && (jq_ <= MM);                        \
        if (!valid_) { qn0=qn1=qn2=qn3=0.f; mn=NEGI; }                        \
        if (!isProd && lane == 63 && jq_ == MM)                               \
            out[0] = LN2f * ((float)mn + log2f((qn0+qn1)+(qn2+qn3)));         \
    }                                                                         \
    if (isProd && lane == 63) {                                               \
        *(float4*)&recOut[sb_][0] = make_float4(qn0,qn1,qn2,qn3);             \
        recOut[sb_][4] = __int_as_float(mn);                                  \
    }                                                                         \
    mD = mU; qd0=qu0; qd1=qu1; qd2=qu2; qd3=qu3;                              \
    mU  = dpp_shr1_i(BM, mn);                                                 \
    qu0 = dpp_shr1_f(BB.x, qn0);                                              \
    qu1 = dpp_shr1_f(BB.y, qn1);                                              \
    qu2 = dpp_shr1_f(BB.z, qn2);                                              \
    qu3 = dpp_shr1_f(BB.w, qn3);                                              \
    mL = mn; ql0=qn0; ql1=qn1; ql2=qn2; ql3=qn3;                              \
} while (0)

// Hoisted record loads (R19): all 4 boundary records of the hc, batched.
#define LOADREC(H)                                                            \
    const int sbh_ = (((H) >> 1) & 3) * 8 + ((H) & 1) * 4;                    \
    float4 bb0_ = make_float4(0.f,0.f,0.f,0.f), bb1_ = bb0_,                  \
           bb2_ = bb0_, bb3_ = bb0_;                                          \
    int bm0_ = NEGI, bm1_ = NEGI, bm2_ = NEGI, bm3_ = NEGI;                   \
    if (isCons) {                                                             \
        bb0_ = *(const float4*)&recIn[sbh_+0][0];                             \
        bb1_ = *(const float4*)&recIn[sbh_+1][0];                             \
        bb2_ = *(const float4*)&recIn[sbh_+2][0];                             \
        bb3_ = *(const float4*)&recIn[sbh_+3][0];                             \
        bm0_ = __float_as_int(recIn[sbh_+0][4]);                              \
        bm1_ = __float_as_int(recIn[sbh_+1][4]);                              \
        bm2_ = __float_as_int(recIn[sbh_+2][4]);                              \
        bm3_ = __float_as_int(recIn[sbh_+3][4]);                              \
    }

// chain tail: LDS-only progress post (NOT in vmcnt stream; wv3 mirrors it).
#define CHCTAIL(H) do {                                                       \
    asm volatile("" ::: "memory");                                            \
    if (lane == 0) *(volatile int*)&flags[F_CDONE] = (H);                     \
} while (0)

#define COMPUTEHC_C(H, PX) do {                                               \
    LOADREC(H);                                                               \
    VSTEP(H,0,PX,1,1,bb0_,bm0_); VSTEP(H,1,PX,1,1,bb1_,bm1_);                 \
    VSTEP(H,2,PX,1,1,bb2_,bm2_); VSTEP(H,3,PX,1,1,bb3_,bm3_);                 \
    CHCTAIL(H);                                                               \
} while (0)

// FAST: all lanes valid; normalize every other step (last step normalized).
#define COMPUTEHC_F(H, PX) do {                                               \
    LOADREC(H);                                                               \
    VSTEP(H,0,PX,0,0,bb0_,bm0_); VSTEP(H,1,PX,0,1,bb1_,bm1_);                 \
    VSTEP(H,2,PX,0,0,bb2_,bm2_); VSTEP(H,3,PX,0,1,bb3_,bm3_);                 \
    CHCTAIL(H);                                                               \
} while (0)

// steady-state body pair (17 vmem LOADS/body: 1 flag + 16 data; NO stores):
// at body h entry outstanding = {F(h+2), D(h)x16, F(h+3), D(h+1)x16} = 34.
// WAITV(33) retires F(h+2); re-issue flag -> 34; WAITV(18) retires D(h)x16
// leaving {F(h+3), D(h+1), F(h+4)} = 18. COMPUTE(h); ISSUE_DATA(h+2) -> 34.
#define CHAINBODY(H, CHC) do {                                                \
    CHUNKSPIN(H);                                                             \
    WAITV(33); CHECK_FLAG(fA, (H)+2); ISSUE_FLAG(fA, (H)+4);                  \
    WAITV(18); CHC((H), pA); ISSUE_DATA(pA, (H)+2);                           \
    WAITV(33); CHECK_FLAG(fB, (H)+3); ISSUE_FLAG(fB, (H)+5);                  \
    WAITV(18); CHC((H)+1, pB); ISSUE_DATA(pB, (H)+3);                         \
} while (0)

__global__ __launch_bounds__(256, 1) void viterbi_r21(
    const float* __restrict__ theta, const float* __restrict__ A,
    float* __restrict__ out, float* __restrict__ bnd, int* __restrict__ prog,
    int* __restrict__ cpG, int* __restrict__ rfG, float* __restrict__ ringG)
{
    __shared__ float  recIn[32][8];
    __shared__ float  recOut[32][8];
    __shared__ int    flags[16];
    extern __shared__ char dynpad[];            // 96 KB pad -> 1 block/CU
    (void)dynpad;

    const int tid  = threadIdx.x;
    const int wv   = tid >> 6;
    const int lane = tid & 63;
    const int bid  = blockIdx.x;

    if (tid < 16) flags[tid] = -1;
    __syncthreads();

    if (bid >= 16) {
        // ===================== producer blocks (4 waves) ====================
        const int k     = bid & 7;           // XCD (heuristic)
        const int idx   = (bid - 16) >> 3;   // 0..29 within XCD
        const int s     = 2*k + (idx >= PPS);
        const int pslot = idx % PPS;
        const int u2    = wv;                // tau within hc
        const int row   = s*64 + lane;
        const float4* A4 = (const float4*)A;
        const float4* T4 = (const float4*)theta;
        const int* cp = cpG + s*16;
        for (int h = pslot; h < HCT; h += PPS) {
            // slots 0..DEPTH-1 free by construction; pace only after wrap.
            while (h >= DEPTH && ld_cohi(cp) < h - DEPTH)
                __builtin_amdgcn_s_sleep(1);
            const int tau = 4*h + u2;
            int c = tau - lane; c = c < 0 ? 0 : (c > MM-1 ? MM-1 : c);
            const float4* Ar = A4 + ((size_t)row*MM + (size_t)c)*4;
            float4 a0 = Ar[0], a1 = Ar[1], a2 = Ar[2], a3 = Ar[3];
            float4 th = T4[(size_t)row*MM + (size_t)c];
            float4 p0, p1, p2, p3;       // theta-folded exp-domain potentials
            p0.x=exp2f((a0.x+th.x)*LOG2E); p0.y=exp2f((a0.y+th.x)*LOG2E);
            p0.z=exp2f((a0.z+th.x)*LOG2E); p0.w=exp2f((a0.w+th.x)*LOG2E);
            p1.x=exp2f((a1.x+th.y)*LOG2E); p1.y=exp2f((a1.y+th.y)*LOG2E);
            p1.z=exp2f((a1.z+th.y)*LOG2E); p1.w=exp2f((a1.w+th.y)*LOG2E);
            p2.x=exp2f((a2.x+th.z)*LOG2E); p2.y=exp2f((a2.y+th.z)*LOG2E);
            p2.z=exp2f((a2.z+th.z)*LOG2E); p2.w=exp2f((a2.w+th.z)*LOG2E);
            p3.x=exp2f((a3.x+th.w)*LOG2E); p3.y=exp2f((a3.y+th.w)*LOG2E);
            p3.z=exp2f((a3.z+th.w)*LOG2E); p3.w=exp2f((a3.w+th.w)*LOG2E);
            float* dst = ringG + ((size_t)(s*DEPTH + (h & (DEPTH-1))) << 12)
                               + (size_t)((u2*4)*64 + lane)*4;
            st_cohf(dst+0,   p0.x); st_cohf(dst+1,   p0.y);
            st_cohf(dst+2,   p0.z); st_cohf(dst+3,   p0.w);
            st_cohf(dst+256, p1.x); st_cohf(dst+257, p1.y);
            st_cohf(dst+258, p1.z); st_cohf(dst+259, p1.w);
            st_cohf(dst+512, p2.x); st_cohf(dst+513, p2.y);
            st_cohf(dst+514, p2.z); st_cohf(dst+515, p2.w);
            st_cohf(dst+768, p3.x); st_cohf(dst+769, p3.y);
            st_cohf(dst+770, p3.z); st_cohf(dst+771, p3.w);
            asm volatile("s_waitcnt vmcnt(0)" ::: "memory");
            if (lane == 0)
                st_cohi(rfG + (size_t)(s*DEPTH + (h & (DEPTH-1)))*16 + u2, h);
        }
        return;
    }

    // ===================== pipeline blocks =====================
    const int strip = ((bid & 7) << 1) | (bid >> 3);
    const bool isCons = (strip > 0);
    const bool isProd = (strip < 15);

    float* Prec = bnd + (size_t)strip * MM * 8;
    const float* Crec = bnd + (size_t)(strip - 1) * MM * 8;
    int* myflag = prog + strip * 32;
    const int* upflag = prog + (strip - 1) * 32;

    if (wv == 0) {
        // ===== chain wave: 2-deep pure-load counted pipeline (no stores) ====
        __builtin_amdgcn_s_setprio(1);
        const int r = lane;
        int   mL = NEGI, mU = NEGI, mD = NEGI;
        float ql0=0,ql1=0,ql2=0,ql3=0;
        float qu0=0,qu1=0,qu2=0,qu3=0;
        float qd0=0,qd1=0,qd2=0,qd3=0;
        if (strip == 0 && lane == 0) { mD = 0; qd0=qd1=qd2=qd3=1.f; }
        if (isCons) {
            while (ld_cohi(upflag) < 1) __builtin_amdgcn_s_sleep(1);
            asm volatile("" ::: "memory");
            qu0 = ld_cohf(Crec+0); qu1 = ld_cohf(Crec+1);
            qu2 = ld_cohf(Crec+2); qu3 = ld_cohf(Crec+3);
            mU  = ld_cohi((const int*)Crec + 4);
        }
        const int* rfS = rfG + (size_t)strip * DEPTH * 16;
        const char* ringS = (const char*)ringG + ((size_t)strip * DEPTH << 14);

        f32x4 pA[16], pB[16];
        i32x4 fA = {-2,-2,-2,-2}, fB = {-2,-2,-2,-2};
        // prologue: slots 0,1 data; flags for 2,3 in flight.
        // (CHECK_FLAG(fB,1) internally drains vmcnt -> D0 retired here.)
        CHECK_FLAG(fA, 0); ISSUE_DATA(pA, 0);
        CHECK_FLAG(fB, 1); ISSUE_DATA(pB, 1);
        ISSUE_FLAG(fA, 2); ISSUE_FLAG(fB, 3);
        // body 0: outstanding {D1x16, F2, F3}=18 -> WAITV(1) retires D1+F2
        // (one-time early D1 drain; producers are far ahead, prologue-only)
        CHUNKSPIN(0);
        WAITV(1);  CHECK_FLAG(fA, 2); ISSUE_FLAG(fA, 4);
        COMPUTEHC_C(0, pA); ISSUE_DATA(pA, 2);
        // body 1: outstanding {F3, F4, D2x16}=18 -> WAITV(17) retires F3
        WAITV(17); CHECK_FLAG(fB, 3); ISSUE_FLAG(fB, 5);
        COMPUTEHC_C(1, pB); ISSUE_DATA(pB, 3);
        // clamped prologue: hc 2..15 (taus 8..63)
        for (int h = 2; h < 16; h += 2)  CHAINBODY(h, COMPUTEHC_C);
        // fast body: hc 16..255 (taus 64..1023, all lanes valid)
        for (int h = 16; h < 256; h += 2) CHAINBODY(h, COMPUTEHC_F);
        // clamped epilogue: hc 256..271 (taus 1024..1087)
        for (int h = 256; h < HCT; h += 2) CHAINBODY(h, COMPUTEHC_C);
    } else if (wv == 1) {
        // ===================== out-comms wave =====================
        if (!isProd) return;
        const int rec0 = lane / 5, wd0 = lane % 5;
        const int rec1 = (lane+64) / 5, wd1 = (lane+64) % 5;
        const bool on1 = (lane + 64) < 80;
        for (int cc = 0; cc < NCH; cc += 2) {
            while (lds_acq(&flags[F_CDONE]) < 2*cc + 3) __builtin_amdgcn_s_sleep(1);
            {
                int col = 8*(cc + (rec0 >> 3)) + (rec0 & 7) - 62;
                float v = recOut[(cc & 3)*8 + rec0][wd0];
                if (col >= 1 && col <= MM) st_cohf(Prec + (size_t)(col-1)*8 + wd0, v);
            }
            if (on1) {
                int col = 8*(cc + (rec1 >> 3)) + (rec1 & 7) - 62;
                float v = recOut[(cc & 3)*8 + rec1][wd1];
                if (col >= 1 && col <= MM) st_cohf(Prec + (size_t)(col-1)*8 + wd1, v);
            }
            asm volatile("s_waitcnt vmcnt(0)" ::: "memory");
            int done = 8*(cc + 1) - 55; if (done > MM) done = MM;
            if (done >= 1 && lane == 0) st_cohi(myflag, done);
            if (lane == 0) lds_rel(&flags[F_OPUB], cc + 1);
        }
    } else if (wv == 2) {
        // ===================== in-comms wave =====================
        if (!isCons) return;
        const int rec0 = lane / 5, wd0 = lane % 5;
        const int rec1 = (lane+64) / 5, wd1 = (lane+64) % 5;
        const bool on1 = (lane + 64) < 80;
        for (int cc = 0; cc < NCH; cc += 2) {
            while (lds_acq(&flags[F_CDONE]) < 2*cc - 3) __builtin_amdgcn_s_sleep(1);
            int need = 8*cc + 17; if (need > MM) need = MM;
            while (ld_cohi(upflag) < need) __builtin_amdgcn_s_sleep(1);
            asm volatile("" ::: "memory");
            {
                int col = 8*cc + 2 + rec0; if (col > MM) col = MM;
                float v = ld_cohf(Crec + (size_t)(col-1)*8 + wd0);
                recIn[(cc & 3)*8 + rec0][wd0] = v;
            }
            if (on1) {
                int col = 8*cc + 2 + rec1; if (col > MM) col = MM;
                float v = ld_cohf(Crec + (size_t)(col-1)*8 + wd1);
                recIn[(cc & 3)*8 + rec1][wd1] = v;
            }
            if (lane == 0) lds_rel(&flags[F_RIN], cc + 1);
        }
    } else {
        // ===================== pace wave (wv3): F_CDONE -> cpG mirror =======
        int* cp = cpG + strip*16;
        if (lane == 0) {
            int last = -2;
            for (;;) {
                int v = lds_acq(&flags[F_CDONE]);
                if (v != last) { st_cohi(cp, v); last = v; }
                if (v >= HCT - 1) break;
                __builtin_amdgcn_s_sleep(1);
            }
        }
    }
}

extern "C" void kernel_launch(void* const* d_in, const int* in_sizes, int n_in,
                              void* d_out, int out_size, void* d_ws, size_t ws_size,
                              hipStream_t stream) {
    const float* theta = (const float*)d_in[0];   // [1024,1024,4] f32
    const float* A     = (const float*)d_in[1];   // [1024,1024,4,4] f32
    float* out = (float*)d_out;                   // [1] f32
    // ws layout (0xAA poison -> all flags/counters negative -> safe spins):
    //   [0, 512K)        boundary records [16][1024][8] f32
    //   [512K, 512K+4K)  record progress flags prog[16*32]
    //   [+4K, +8K)       chain progress cpG[16*16]
    //   [+8K, +40K)      ring flags rfG[16*32*16]
    //   [64K-aligned 8M) P ring ringG: 16 strips * 32 slots * 16 KB
    char* base = (char*)d_ws;
    float* bnd  = (float*)base;
    int*   prog = (int*)(base + (size_t)512*1024);
    int*   cpG  = (int*)(base + (size_t)512*1024 + 4*1024);
    int*   rfG  = (int*)(base + (size_t)512*1024 + 8*1024);
    float* ring = (float*)(base + (size_t)512*1024 + 64*1024);
    // 96 KB dynamic LDS pad: 1 block/CU for all 256 blocks.
    viterbi_r21<<<256, 256, 96*1024, stream>>>(theta, A, out, bnd, prog,
                                               cpG, rfG, ring);
}